// Round 14
// baseline (118.643 us; speedup 1.0000x reference)
//
#include <hip/hip_runtime.h>
#include <hip/hip_bf16.h>

typedef unsigned long long ull;

#define MGRID 48
#define CCH   256
#define NCELL 2304      // 48*48
#define NA    6912      // anchors
#define NW    108       // NA/64
#define NHID  1024
#define KFC   2304      // 9*256
#define RPOST 512
#define IMGF  1536.0f
#define NQ2   6099      // triangular iou groups, band w+2: G(107)=5991 + 108
#define IOUB  1220      // ceil(NQ2/5) blocks at 320 threads (5 groups each)

typedef __attribute__((ext_vector_type(8))) short short8v;  // 8 bf16
typedef __attribute__((ext_vector_type(4))) float f32x4;

// ---------------- K1: RPN head + anchor_prep (blocks 0..191) + wcvt (192..2495)
//                    + rank_acc/done zeroing (block 0; replay-safe) ----------------
__global__ __launch_bounds__(256) void rpn_anchor_wcvt(const float* __restrict__ feat,
    const float* __restrict__ Wobj, const float* __restrict__ bobj,
    const float* __restrict__ Wreg, const float* __restrict__ breg,
    const float* __restrict__ anchors, float* __restrict__ probs,
    float* __restrict__ boxes, ull* __restrict__ keys,
    const float* __restrict__ Wfc1, ushort* __restrict__ Wt,
    unsigned* __restrict__ rank_acc){
  int t = threadIdx.x;
  if (blockIdx.x >= 192){
    __shared__ float tile[32][33];
    int bid = blockIdx.x - 192;
    int bx = bid & 31;          // n-tile (32 cols of W), 32
    int by = bid >> 5;          // k-tile (32 rows of W), 72
    int tx = t & 31, ty = t >> 5;
    #pragma unroll
    for (int it=0; it<4; ++it)
      tile[ty + 8*it][tx] = Wfc1[(size_t)(by*32 + ty + 8*it)*NHID + bx*32 + tx];
    __syncthreads();
    #pragma unroll
    for (int it=0; it<4; ++it){
      __hip_bfloat16 b = __float2bfloat16(tile[tx][ty + 8*it]);
      Wt[(size_t)(bx*32 + ty + 8*it)*KFC + by*32 + tx] = *(ushort*)&b;
    }
    return;
  }
  if (blockIdx.x == 0){         // zero rank accumulators + iou done counter (every call)
    for (int i = t; i < NA + 1; i += 256) rank_acc[i] = 0u;
  }
  __shared__ float rpn_lds[12*18];
  int cell0 = blockIdx.x * 12;
  if (t < 216){
    int lc = t / 18, o = t % 18;
    const float* W; int stride; float acc;
    if (o < 6){ W = Wobj + o; stride = 6;  acc = bobj[o];   }
    else      { W = Wreg + (o-6); stride = 12; acc = breg[o-6]; }
    const float4* x4 = (const float4*)(feat + (cell0 + lc)*CCH);
    #pragma unroll 4
    for (int c4=0;c4<CCH/4;++c4){
      float4 xv = x4[c4];
      acc += xv.x*W[(4*c4+0)*stride];
      acc += xv.y*W[(4*c4+1)*stride];
      acc += xv.z*W[(4*c4+2)*stride];
      acc += xv.w*W[(4*c4+3)*stride];
    }
    rpn_lds[t] = acc;
  }
  __syncthreads();
  if (t < 36){
    int a = cell0*3 + t;
    int k = t % 3;
    const float* rc = rpn_lds + (t/3)*18;
    float l0 = rc[2*k], l1 = rc[2*k+1];
    float m  = fmaxf(l0,l1);
    float e0 = expf(l0-m), e1 = expf(l1-m);
    float s  = e0 + e1;
    float p0 = e0/s, p1 = e1/s;
    probs[a*2+0] = p0; probs[a*2+1] = p1;
    float4 an = ((const float4*)anchors)[a];
    float r0 = rc[6+4*k+0], r1 = rc[6+4*k+1], r2 = rc[6+4*k+2], r3 = rc[6+4*k+3];
    float cxa = an.x + an.z*0.5f, cya = an.y + an.w*0.5f;
    float cx = r0*an.z + cxa, cy = r1*an.w + cya;
    float w  = an.z*expf(r2),  hh = an.w*expf(r3);
    float bx = cx - w*0.5f, by = cy - hh*0.5f;
    float x1 = fminf(fmaxf(bx,      0.0f), IMGF);
    float y1 = fminf(fmaxf(by,      0.0f), IMGF);
    float x2 = fminf(fmaxf(bx + w,  0.0f), IMGF);
    float y2 = fminf(fmaxf(by + hh, 0.0f), IMGF);
    float4 bo; bo.x = x1; bo.y = y1; bo.z = x2 - x1; bo.w = y2 - y1;
    ((float4*)boxes)[a] = bo;
    keys[a] = ((ull)__float_as_uint(p1) << 32) | (unsigned)(NA-1-a);  // stable argsort key
  }
}

// ---------------- K2: FUSED rank: partial count + 27th-arriver scatter (NO spin) ----------------
__global__ __launch_bounds__(256) void rank_fused(const ull* __restrict__ keys,
    const float* __restrict__ boxes, unsigned* __restrict__ rank_acc,
    int* __restrict__ ord, float* __restrict__ sboxes){
  __shared__ ull lk[256];
  int t = threadIdx.x;
  int ib = blockIdx.x, jb = blockIdx.y;
  lk[t] = keys[jb*256 + t];
  int i = ib*256 + t;
  ull ki = keys[i];
  __syncthreads();
  int cnt = 0;
  #pragma unroll 16
  for (int j=0;j<256;++j) cnt += (lk[j] > ki) ? 1 : 0;
  unsigned old = atomicAdd(&rank_acc[i], (unsigned)cnt | (1u<<16));
  if ((old >> 16) == 26u){                    // last of 27 contributions
    int r = (int)(old & 0xFFFFu) + cnt;
    ord[r] = i;
    ((float4*)sboxes)[r] = ((const float4*)boxes)[i];
  }
}

// ---------------- K3: IoU bitmask (+2 subdiag band) FUSED with NMS via last-arriver ----------------
// iou: 320 threads = 5 groups of 64; 1220 blocks cover NQ2 groups.
// After storing, each block fences + atomicAdd(done). The LAST block (old==IOUB-1)
// — exactly one block, zero spin — acquires and runs the proven r13 NMS inline.
__device__ inline int Gfun2(int w){ return (w <= 105) ? (w*(w+5))/2 : 5775 + (w-105)*108; }
__global__ __launch_bounds__(320) void iou_nms(const float* __restrict__ sboxes,
    ull* __restrict__ maskT, const int* __restrict__ ord,
    const float* __restrict__ probs, float* __restrict__ out,
    float* __restrict__ selb, unsigned* __restrict__ done){
  int t = threadIdx.x;
  // ---- iou phase ----
  {
    int q = blockIdx.x*5 + (t >> 6);
    if (q < NQ2){
      int w = (int)((sqrtf(8.0f*(float)q + 25.0f) - 5.0f) * 0.5f);
      if (w < 0) w = 0;
      if (w > 107) w = 107;
      while (w < 107 && Gfun2(w+1) <= q) ++w;
      while (w > 0 && Gfun2(w) > q) --w;
      int ib = q - Gfun2(w);
      int i = ib*64 + (t & 63);
      float4 bi = ((const float4*)sboxes)[i];
      float x1i = bi.x, y1i = bi.y;
      float x2i = bi.x + bi.z, y2i = bi.y + bi.w;
      float ai  = (x2i - x1i) * (y2i - y1i);
      const float4* bj4 = (const float4*)sboxes + w*64;
      ull bits = 0;
      #pragma unroll 8
      for (int jj=0;jj<64;++jj){
        float4 bj = bj4[jj];                  // uniform across wave -> broadcast
        float x1j = bj.x, y1j = bj.y;
        float x2j = bj.x + bj.z, y2j = bj.y + bj.w;
        float aj  = (x2j - x1j) * (y2j - y1j);
        float iw = fmaxf(fminf(x2i,x2j) - fmaxf(x1i,x1j), 0.0f);
        float ih = fmaxf(fminf(y2i,y2j) - fmaxf(y1i,y1j), 0.0f);
        float inter = iw*ih;
        float den = ai + aj - inter + 1e-8f;
        if (inter > 0.3f*den) bits |= (1ull<<jj);
      }
      maskT[(size_t)w*NA + i] = bits;
    }
  }
  __syncthreads();
  __shared__ int islast;
  if (t == 0){
    __threadfence();                          // release this block's maskT rows
    unsigned old = atomicAdd(done, 1u);
    islast = (old == (unsigned)(IOUB - 1)) ? 1 : 0;
  }
  __syncthreads();
  if (!islast) return;
  __threadfence();                            // acquire all maskT

  // ---- NMS phase (r13 proven body; depth-2 srow + remv register-prefetch) ----
  __shared__ ull remv[NW];
  __shared__ ull keepw[NW];
  __shared__ ull kb_sh[2];
  __shared__ int selpos[RPOST];
  __shared__ int base_sh[NW];
  __shared__ int cnt_sh, done_sh;
  if (t < NW){ remv[t] = 0ull; keepw[t] = 0ull; }
  if (t == 0){ cnt_sh = 0; done_sh = 0; kb_sh[0] = 0ull; kb_sh[1] = 0ull; }
  __syncthreads();

  ull dg_cur = 0, s1_cur = 0, s2_cur = 0, kbp1 = 0, kbp2 = 0, remv_c = 0;
  ulonglong2 pre[16];                      // 32 source rows (static idx only)
  #pragma unroll
  for (int b=0;b<16;++b){ pre[b].x = 0ull; pre[b].y = 0ull; }
  if (t < 64) dg_cur = maskT[t];

  const int u  = t - 64;                   // worker id 0..255
  const int pw = u >> 1;                   // word offset
  const int hh = u & 1;                    // half of the 64 source rows

  for (int c = 0; c < NW; ++c){
    if (t < 64){
      ull dg_n = 0, s1_n = 0, s2_n = 0;
      if (c+1 < NW){
        dg_n = maskT[(size_t)(c+1)*NA + (size_t)(c+1)*64 + t];
        s1_n = maskT[(size_t)c*NA     + (size_t)(c+1)*64 + t];
        s2_n = (c >= 1) ? maskT[(size_t)(c-1)*NA + (size_t)(c+1)*64 + t] : 0ull;
      }
      ull remv_n = (c+1 < NW) ? remv[c+1] : 0ull;   // final since end of chunk c-1
      bool dec  = ((remv_c >> t) & 1ull) || ((s1_cur & kbp1) != 0ull)
                                         || ((s2_cur & kbp2) != 0ull);
      bool kept = false;
      ull sup = dg_cur & ((1ull << t) - 1ull);
      for (;;){
        ull K = __ballot(kept);
        ull D = __ballot(dec);
        if (D == ~0ull) break;
        if (!dec){
          if (sup & K)                 { dec = true; }
          else if ((sup & ~D) == 0ull) { dec = true; kept = true; }
        }
      }
      ull kb = __ballot(kept);
      int cnt0 = cnt_sh;
      ull below = kb & ((1ull << t) - 1ull);
      int myrank = cnt0 + __popcll(below);
      if (kept && myrank < RPOST) selpos[myrank] = c*64 + t;
      if (t == 0){
        kb_sh[c & 1] = kb;
        keepw[c] = kb;
        int nc = cnt0 + __popcll(kb);
        if (nc >= RPOST){ nc = RPOST; done_sh = 1; }
        cnt_sh = nc;
      }
      kbp2 = kbp1; kbp1 = kb;
      dg_cur = dg_n; s1_cur = s1_n; s2_cur = s2_n; remv_c = remv_n;
    } else {
      int wpc = c + 2 + pw;
      if (c >= 1 && wpc < NW){
        ull kbp = kb_sh[(c-1) & 1];
        if (kbp){
          ull acc = 0;
          #pragma unroll
          for (int b=0;b<16;++b){
            acc |= (0ull - ((kbp >> (hh*32 + 2*b))   & 1ull)) & pre[b].x;
            acc |= (0ull - ((kbp >> (hh*32 + 2*b+1)) & 1ull)) & pre[b].y;
          }
          if (acc) atomicOr(&remv[wpc], acc);
        }
      }
      int wpn = c + 3 + pw;
      if (c+1 < NW && wpn < NW){
        const ulonglong2* src =
          (const ulonglong2*)(maskT + (size_t)wpn*NA + (size_t)c*64) + hh*16;
        #pragma unroll
        for (int b=0;b<16;++b) pre[b] = src[b];
      }
    }
    __syncthreads();
    if (done_sh) break;
  }
  __syncthreads();
  int cnt0 = cnt_sh;
  if (cnt0 < RPOST){
    if (t < NW){
      int s = 0;
      for (int w2=0; w2<t; ++w2) s += __popcll(~keepw[w2]);
      base_sh[t] = s;
    }
    __syncthreads();
    for (int p = t; p < NA; p += 320){
      int w2 = p >> 6, b = p & 63;
      ull kw = keepw[w2];
      if (!((kw >> b) & 1ull)){
        int rank = cnt0 + base_sh[w2] + __popcll(~kw & ((1ull << b) - 1ull));
        if (rank < RPOST) selpos[rank] = p;
      }
    }
  }
  __syncthreads();
  for (int s=t; s<RPOST; s+=320){
    int pos = selpos[s];
    int orig = ord[pos];
    float4 b = ((const float4*)sboxes)[pos];
    out[s*10+0] = probs[orig*2+0];
    out[s*10+1] = probs[orig*2+1];
    out[s*10+2] = b.x; out[s*10+3] = b.y; out[s*10+4] = b.z; out[s*10+5] = b.w;
    ((float4*)selb)[s] = b;
  }
}

// ---------------- K4: ROIAlign (block = box, thread = channel) -> bf16 pooled ----------------
__global__ __launch_bounds__(256) void roialign(const float* __restrict__ feat,
    const float* __restrict__ selb, __hip_bfloat16* __restrict__ pooled){
  int r = blockIdx.x, c = threadIdx.x;
  float4 b = ((const float4*)selb)[r];
  int x0[6], x1[6], y0[6], y1[6];
  float wx[6], wy[6];
  #pragma unroll
  for (int s=0;s<6;++s){
    float off = ((float)s + 0.5f) / 6.0f;
    float fx = (b.x + off*b.z) / 32.0f - 0.5f;
    fx = fminf(fmaxf(fx, 0.0f), 47.0f);
    int xx0 = (int)floorf(fx);
    x0[s] = xx0; x1[s] = min(xx0+1, 47); wx[s] = fx - (float)xx0;
    float fy = (b.y + off*b.w) / 32.0f - 0.5f;
    fy = fminf(fmaxf(fy, 0.0f), 47.0f);
    int yy0 = (int)floorf(fy);
    y0[s] = yy0; y1[s] = min(yy0+1, 47); wy[s] = fy - (float)yy0;
  }
  #pragma unroll
  for (int ty=0;ty<3;++ty){
    #pragma unroll
    for (int tx=0;tx<3;++tx){
      float sum = 0.0f;
      #pragma unroll
      for (int py=0;py<2;++py){
        #pragma unroll
        for (int px=0;px<2;++px){
          int sy = ty*2+py, sx = tx*2+px;
          float wxx = wx[sx], wyy = wy[sy];
          float v00 = feat[(y0[sy]*MGRID + x0[sx])*CCH + c];
          float v01 = feat[(y0[sy]*MGRID + x1[sx])*CCH + c];
          float v10 = feat[(y1[sy]*MGRID + x0[sx])*CCH + c];
          float v11 = feat[(y1[sy]*MGRID + x1[sx])*CCH + c];
          sum += v00*(1.0f-wyy)*(1.0f-wxx) + v01*(1.0f-wyy)*wxx
               + v10*wyy*(1.0f-wxx)        + v11*wyy*wxx;
        }
      }
      pooled[((r*9) + ty*3 + tx)*CCH + c] = __float2bfloat16(sum * 0.25f);
    }
  }
}

// ---------------- K5: FC1 bf16 MFMA, 2-way K-split ----------------
__global__ __launch_bounds__(256) void fc1_mfma(const ushort* __restrict__ A,
    const ushort* __restrict__ Bt, const float* __restrict__ bias,
    float* __restrict__ Hp){
  __shared__ ushort As[4096];   // 64 rows x 64 k bf16, XOR-swizzled 16B chunks
  __shared__ ushort Bs[4096];
  const int t = threadIdx.x;
  const int bn = blockIdx.x, bm = blockIdx.y, bz = blockIdx.z;
  const int wv = t >> 6, lane = t & 63;
  const int wm = (wv >> 1) * 32, wn = (wv & 1) * 32;

  const int r0 = t >> 3, kc = t & 7;
  const int r1 = r0 + 32;
  const int kbase = bz * 144;   // 1152 k * 2B / 16B
  const float4* gA0 = (const float4*)A  + (size_t)(bm*64 + r0)*288 + kbase + kc;
  const float4* gA1 = (const float4*)A  + (size_t)(bm*64 + r1)*288 + kbase + kc;
  const float4* gB0 = (const float4*)Bt + (size_t)(bn*64 + r0)*288 + kbase + kc;
  const float4* gB1 = (const float4*)Bt + (size_t)(bn*64 + r1)*288 + kbase + kc;
  float4* sA0 = (float4*)As + ((r0<<3) | (kc ^ (r0&7)));
  float4* sA1 = (float4*)As + ((r1<<3) | (kc ^ (r1&7)));
  float4* sB0 = (float4*)Bs + ((r0<<3) | (kc ^ (r0&7)));
  float4* sB1 = (float4*)Bs + ((r1<<3) | (kc ^ (r1&7)));

  const int fr = lane & 15, fkg = lane >> 4;
  const int arow0 = wm + fr,      arow1 = wm + 16 + fr;
  const int brow0 = wn + fr,      brow1 = wn + 16 + fr;

  f32x4 acc00{}, acc01{}, acc10{}, acc11{};

  const int KT = 18;            // 1152 / 64
  float4 pa0 = gA0[0], pa1 = gA1[0], pb0 = gB0[0], pb1 = gB1[0];
  for (int kt = 0; kt < KT; ++kt){
    __syncthreads();
    *sA0 = pa0; *sA1 = pa1; *sB0 = pb0; *sB1 = pb1;
    if (kt + 1 < KT){
      pa0 = gA0[(kt+1)*8]; pa1 = gA1[(kt+1)*8];
      pb0 = gB0[(kt+1)*8]; pb1 = gB1[(kt+1)*8];
    }
    __syncthreads();
    #pragma unroll
    for (int kk2 = 0; kk2 < 2; ++kk2){
      int kidx = fkg + kk2*4;
      short8v a0 = *(const short8v*)(As + ((((arow0<<3) | (kidx ^ (arow0&7)))) << 3));
      short8v a1 = *(const short8v*)(As + ((((arow1<<3) | (kidx ^ (arow1&7)))) << 3));
      short8v b0 = *(const short8v*)(Bs + ((((brow0<<3) | (kidx ^ (brow0&7)))) << 3));
      short8v b1 = *(const short8v*)(Bs + ((((brow1<<3) | (kidx ^ (brow1&7)))) << 3));
      acc00 = __builtin_amdgcn_mfma_f32_16x16x32_bf16(a0, b0, acc00, 0, 0, 0);
      acc01 = __builtin_amdgcn_mfma_f32_16x16x32_bf16(a0, b1, acc01, 0, 0, 0);
      acc10 = __builtin_amdgcn_mfma_f32_16x16x32_bf16(a1, b0, acc10, 0, 0, 0);
      acc11 = __builtin_amdgcn_mfma_f32_16x16x32_bf16(a1, b1, acc11, 0, 0, 0);
    }
  }
  float* H = Hp + (size_t)bz * 512 * NHID;
  const int orow = bm*64 + wm + (lane>>4)*4;
  const int ocol = bn*64 + wn + (lane&15);
  #pragma unroll
  for (int i=0;i<2;++i){
    #pragma unroll
    for (int j=0;j<2;++j){
      f32x4 a = (i==0) ? ((j==0)?acc00:acc01) : ((j==0)?acc10:acc11);
      #pragma unroll
      for (int reg=0;reg<4;++reg){
        int row = orow + i*16 + reg;
        int col = ocol + j*16;
        float v = a[reg] + (bz == 0 ? bias[col] : 0.0f);
        H[(size_t)row*NHID + col] = v;        // relu deferred to fc2
      }
    }
  }
}

// ---------------- K6: FC2 (sums K-split partials + relu) + unparameterize ----------------
__global__ __launch_bounds__(64) void fc2(const float* __restrict__ h0,
    const float* __restrict__ h1, const float* __restrict__ W2,
    const float* __restrict__ b2, const float* __restrict__ selb,
    float* __restrict__ out){
  int r = blockIdx.x, lane = threadIdx.x;
  float a0=0,a1=0,a2=0,a3=0;
  #pragma unroll 4
  for (int it=0; it<16; ++it){
    int k = it*64 + lane;
    float hv = fmaxf(h0[(size_t)r*NHID + k] + h1[(size_t)r*NHID + k], 0.0f);
    float4 w = ((const float4*)W2)[k];
    a0 += hv*w.x; a1 += hv*w.y; a2 += hv*w.z; a3 += hv*w.w;
  }
  #pragma unroll
  for (int off=32; off>0; off>>=1){
    a0 += __shfl_down(a0, off);
    a1 += __shfl_down(a1, off);
    a2 += __shfl_down(a2, off);
    a3 += __shfl_down(a3, off);
  }
  if (lane == 0){
    float4 b = ((const float4*)selb)[r];
    float r0 = a0 + b2[0], r1 = a1 + b2[1], r2 = a2 + b2[2], r3 = a3 + b2[3];
    float cxa = b.x + b.z*0.5f, cya = b.y + b.w*0.5f;
    float cx = r0*b.z + cxa, cy = r1*b.w + cya;
    float w  = b.z*expf(r2),  hh = b.w*expf(r3);
    out[r*10+6] = cx - w*0.5f;
    out[r*10+7] = cy - hh*0.5f;
    out[r*10+8] = w;
    out[r*10+9] = hh;
  }
}

extern "C" void kernel_launch(void* const* d_in, const int* in_sizes, int n_in,
                              void* d_out, int out_size, void* d_ws, size_t ws_size,
                              hipStream_t stream) {
  const float* feat    = (const float*)d_in[0];
  const float* anchors = (const float*)d_in[1];
  const float* Wobj    = (const float*)d_in[2];
  const float* bobj    = (const float*)d_in[3];
  const float* Wreg    = (const float*)d_in[4];
  const float* breg    = (const float*)d_in[5];
  const float* Wfc1    = (const float*)d_in[6];
  const float* bfc1    = (const float*)d_in[7];
  const float* Wfc2    = (const float*)d_in[8];
  const float* bfc2    = (const float*)d_in[9];
  float* out = (float*)d_out;
  char* ws = (char*)d_ws;

  float* probs  = (float*)(ws + 165888);     // 55296
  float* boxes  = (float*)(ws + 221184);     // 110592
  ull*   keys   = (ull*)  (ws + 331776);     // 55296
  int*   ord    = (int*)  (ws + 387072);     // 27648
  float* sboxes = (float*)(ws + 414720);     // 110592
  unsigned* rank_acc = (unsigned*)(ws + 525312); // NA+1 words (rank accs + iou done counter)
  ull*   maskT  = (ull*)  (ws + 1271808);    // 5971968
  float* selb   = (float*)(ws + 7243776);    // 8192
  __hip_bfloat16* pooled = (__hip_bfloat16*)(ws + 7251968); // 2359296
  float* h      = (float*)(ws + 9611264);    // 2x 2097152 (K-split partials)
  ushort* Wt    = (ushort*)(ws + 13805568);  // 4718592 (end 18524160)

  unsigned* iou_done = rank_acc + NA;
  float* h0 = h;
  float* h1 = h + 512*NHID;

  hipLaunchKernelGGL(rpn_anchor_wcvt, dim3(2496),  dim3(256), 0, stream,
                     feat, Wobj, bobj, Wreg, breg, anchors, probs, boxes, keys, Wfc1, Wt, rank_acc);
  hipLaunchKernelGGL(rank_fused,   dim3(27,27),  dim3(256), 0, stream, keys, boxes, rank_acc, ord, sboxes);
  hipLaunchKernelGGL(iou_nms,      dim3(IOUB),   dim3(320), 0, stream, sboxes, maskT, ord, probs, out, selb, iou_done);
  hipLaunchKernelGGL(roialign,     dim3(512),    dim3(256), 0, stream, feat, selb, pooled);
  hipLaunchKernelGGL(fc1_mfma,     dim3(16,8,2), dim3(256), 0, stream, (const ushort*)pooled, Wt, bfc1, h);
  hipLaunchKernelGGL(fc2,          dim3(512),    dim3(64),  0, stream, h0, h1, Wfc2, bfc2, selb, out);
}

// Round 15
// 86.692 us; speedup vs baseline: 1.3686x; 1.3686x over previous
//
#include <hip/hip_runtime.h>
#include <hip/hip_bf16.h>

typedef unsigned long long ull;

#define MGRID 48
#define CCH   256
#define NCELL 2304      // 48*48
#define NA    6912      // anchors
#define NW    108       // NA/64
#define NHID  1024
#define KFC   2304      // 9*256
#define RPOST 512
#define IMGF  1536.0f
#define NQ2   6099      // triangular iou groups, band w+2: G(107)=5991 + 108

typedef __attribute__((ext_vector_type(8))) short short8v;  // 8 bf16
typedef __attribute__((ext_vector_type(4))) float f32x4;

// ---------------- K1: RPN head + anchor_prep (blocks 0..191) + wcvt (192..2495)
//                    + rank_acc zeroing (block 0; replay-safe) ----------------
__global__ __launch_bounds__(256) void rpn_anchor_wcvt(const float* __restrict__ feat,
    const float* __restrict__ Wobj, const float* __restrict__ bobj,
    const float* __restrict__ Wreg, const float* __restrict__ breg,
    const float* __restrict__ anchors, float* __restrict__ probs,
    float* __restrict__ boxes, ull* __restrict__ keys,
    const float* __restrict__ Wfc1, ushort* __restrict__ Wt,
    unsigned* __restrict__ rank_acc){
  int t = threadIdx.x;
  if (blockIdx.x >= 192){
    __shared__ float tile[32][33];
    int bid = blockIdx.x - 192;
    int bx = bid & 31;          // n-tile (32 cols of W), 32
    int by = bid >> 5;          // k-tile (32 rows of W), 72
    int tx = t & 31, ty = t >> 5;
    #pragma unroll
    for (int it=0; it<4; ++it)
      tile[ty + 8*it][tx] = Wfc1[(size_t)(by*32 + ty + 8*it)*NHID + bx*32 + tx];
    __syncthreads();
    #pragma unroll
    for (int it=0; it<4; ++it){
      __hip_bfloat16 b = __float2bfloat16(tile[tx][ty + 8*it]);
      Wt[(size_t)(bx*32 + ty + 8*it)*KFC + by*32 + tx] = *(ushort*)&b;
    }
    return;
  }
  if (blockIdx.x == 0){         // zero rank accumulators (every call: replay-safe)
    for (int i = t; i < NA; i += 256) rank_acc[i] = 0u;
  }
  __shared__ float rpn_lds[12*18];
  int cell0 = blockIdx.x * 12;
  if (t < 216){
    int lc = t / 18, o = t % 18;
    const float* W; int stride; float acc;
    if (o < 6){ W = Wobj + o; stride = 6;  acc = bobj[o];   }
    else      { W = Wreg + (o-6); stride = 12; acc = breg[o-6]; }
    const float4* x4 = (const float4*)(feat + (cell0 + lc)*CCH);
    #pragma unroll 4
    for (int c4=0;c4<CCH/4;++c4){
      float4 xv = x4[c4];
      acc += xv.x*W[(4*c4+0)*stride];
      acc += xv.y*W[(4*c4+1)*stride];
      acc += xv.z*W[(4*c4+2)*stride];
      acc += xv.w*W[(4*c4+3)*stride];
    }
    rpn_lds[t] = acc;
  }
  __syncthreads();
  if (t < 36){
    int a = cell0*3 + t;
    int k = t % 3;
    const float* rc = rpn_lds + (t/3)*18;
    float l0 = rc[2*k], l1 = rc[2*k+1];
    float m  = fmaxf(l0,l1);
    float e0 = expf(l0-m), e1 = expf(l1-m);
    float s  = e0 + e1;
    float p0 = e0/s, p1 = e1/s;
    probs[a*2+0] = p0; probs[a*2+1] = p1;
    float4 an = ((const float4*)anchors)[a];
    float r0 = rc[6+4*k+0], r1 = rc[6+4*k+1], r2 = rc[6+4*k+2], r3 = rc[6+4*k+3];
    float cxa = an.x + an.z*0.5f, cya = an.y + an.w*0.5f;
    float cx = r0*an.z + cxa, cy = r1*an.w + cya;
    float w  = an.z*expf(r2),  hh = an.w*expf(r3);
    float bx = cx - w*0.5f, by = cy - hh*0.5f;
    float x1 = fminf(fmaxf(bx,      0.0f), IMGF);
    float y1 = fminf(fmaxf(by,      0.0f), IMGF);
    float x2 = fminf(fmaxf(bx + w,  0.0f), IMGF);
    float y2 = fminf(fmaxf(by + hh, 0.0f), IMGF);
    float4 bo; bo.x = x1; bo.y = y1; bo.z = x2 - x1; bo.w = y2 - y1;
    ((float4*)boxes)[a] = bo;
    keys[a] = ((ull)__float_as_uint(p1) << 32) | (unsigned)(NA-1-a);  // stable argsort key
  }
}

// ---------------- K2: FUSED rank: partial count + 27th-arriver scatter (NO spin) ----------------
// atomicAdd packs (count<<16 | partial-rank). The block whose add is the 27th sees
// old>>16==26, owns the complete rank, and scatters ord/sboxes itself.
__global__ __launch_bounds__(256) void rank_fused(const ull* __restrict__ keys,
    const float* __restrict__ boxes, unsigned* __restrict__ rank_acc,
    int* __restrict__ ord, float* __restrict__ sboxes){
  __shared__ ull lk[256];
  int t = threadIdx.x;
  int ib = blockIdx.x, jb = blockIdx.y;
  lk[t] = keys[jb*256 + t];
  int i = ib*256 + t;
  ull ki = keys[i];
  __syncthreads();
  int cnt = 0;
  #pragma unroll 16
  for (int j=0;j<256;++j) cnt += (lk[j] > ki) ? 1 : 0;
  unsigned old = atomicAdd(&rank_acc[i], (unsigned)cnt | (1u<<16));
  if ((old >> 16) == 26u){                    // last of 27 contributions
    int r = (int)(old & 0xFFFFu) + cnt;
    ord[r] = i;
    ((float4*)sboxes)[r] = ((const float4*)boxes)[i];
  }
}

// ---------------- K3: IoU bitmask, compacted triangle with +2 subdiag band ----------------
// consumed: (i>>6) <= w+2 (diag, srow1, srow2, upper triangle).
// groups(w)=min(w+3,108); G(w)=w(w+5)/2 (w<=105), else 5775+(w-105)*108.
__device__ inline int Gfun2(int w){ return (w <= 105) ? (w*(w+5))/2 : 5775 + (w-105)*108; }
__global__ __launch_bounds__(256) void iou_mask(const float* __restrict__ sboxes,
                                                ull* __restrict__ maskT){
  int g = blockIdx.x*256 + threadIdx.x;
  int q = g >> 6;
  if (q >= NQ2) return;
  int w = (int)((sqrtf(8.0f*(float)q + 25.0f) - 5.0f) * 0.5f);
  if (w < 0) w = 0;
  if (w > 107) w = 107;
  while (w < 107 && Gfun2(w+1) <= q) ++w;
  while (w > 0 && Gfun2(w) > q) --w;
  int ib = q - Gfun2(w);
  int i = ib*64 + (g & 63);
  float4 bi = ((const float4*)sboxes)[i];
  float x1i = bi.x, y1i = bi.y;
  float x2i = bi.x + bi.z, y2i = bi.y + bi.w;
  float ai  = (x2i - x1i) * (y2i - y1i);
  const float4* bj4 = (const float4*)sboxes + w*64;
  ull bits = 0;
  #pragma unroll 8
  for (int jj=0;jj<64;++jj){
    float4 bj = bj4[jj];                      // uniform across wave -> broadcast
    float x1j = bj.x, y1j = bj.y;
    float x2j = bj.x + bj.z, y2j = bj.y + bj.w;
    float aj  = (x2j - x1j) * (y2j - y1j);
    float iw = fmaxf(fminf(x2i,x2j) - fmaxf(x1i,x1j), 0.0f);
    float ih = fmaxf(fminf(y2i,y2j) - fmaxf(y1i,y1j), 0.0f);
    float inter = iw*ih;
    float den = ai + aj - inter + 1e-8f;
    if (inter > 0.3f*den) bits |= (1ull<<jj);
  }
  maskT[(size_t)w*NA + i] = bits;
}

// ---------------- K4: NMS, depth-2 srow + remv register-prefetch ----------------
// Suppression of chunk c by: c-1 (srow1&kb1, regs), c-2 (srow2&kb2, regs),
// <=c-3 (workers: kb(c-1) applied during chunk c to remv[c+2+pw]).
// => remv[c+1] is FINAL at end of chunk c-1, so wave0 reads it during chunk c
// (register-carried into chunk c+1): no dependent LDS read at chunk start.
__global__ __launch_bounds__(320) void nms(const ull* __restrict__ maskT,
    const int* __restrict__ ord, const float* __restrict__ sboxes,
    const float* __restrict__ probs, float* __restrict__ out,
    float* __restrict__ selb){
  __shared__ ull remv[NW];
  __shared__ ull keepw[NW];
  __shared__ ull kb_sh[2];
  __shared__ int selpos[RPOST];
  __shared__ int base_sh[NW];
  __shared__ int cnt_sh, done_sh;
  int t = threadIdx.x;
  if (t < NW){ remv[t] = 0ull; keepw[t] = 0ull; }
  if (t == 0){ cnt_sh = 0; done_sh = 0; kb_sh[0] = 0ull; kb_sh[1] = 0ull; }
  __syncthreads();

  ull dg_cur = 0, s1_cur = 0, s2_cur = 0, kbp1 = 0, kbp2 = 0, remv_c = 0;
  ulonglong2 pre[16];                      // 32 source rows (static idx only)
  #pragma unroll
  for (int b=0;b<16;++b){ pre[b].x = 0ull; pre[b].y = 0ull; }
  if (t < 64) dg_cur = maskT[t];

  const int u  = t - 64;                   // worker id 0..255
  const int pw = u >> 1;                   // word offset
  const int hh = u & 1;                    // half of the 64 source rows

  for (int c = 0; c < NW; ++c){
    if (t < 64){
      // prefetch chunk c+1's rows (addresses independent of the scan)
      ull dg_n = 0, s1_n = 0, s2_n = 0;
      if (c+1 < NW){
        dg_n = maskT[(size_t)(c+1)*NA + (size_t)(c+1)*64 + t];
        s1_n = maskT[(size_t)c*NA     + (size_t)(c+1)*64 + t];
        s2_n = (c >= 1) ? maskT[(size_t)(c-1)*NA + (size_t)(c+1)*64 + t] : 0ull;
      }
      // remv[c+1]: final since end of chunk c-1 (workers now target >= c+2)
      ull remv_n = (c+1 < NW) ? remv[c+1] : 0ull;
      // phase A: register-only ballot fixpoint
      bool dec  = ((remv_c >> t) & 1ull) || ((s1_cur & kbp1) != 0ull)
                                         || ((s2_cur & kbp2) != 0ull);
      bool kept = false;
      ull sup = dg_cur & ((1ull << t) - 1ull);
      for (;;){
        ull K = __ballot(kept);
        ull D = __ballot(dec);
        if (D == ~0ull) break;
        if (!dec){
          if (sup & K)                 { dec = true; }
          else if ((sup & ~D) == 0ull) { dec = true; kept = true; }
        }
      }
      ull kb = __ballot(kept);
      int cnt0 = cnt_sh;
      ull below = kb & ((1ull << t) - 1ull);
      int myrank = cnt0 + __popcll(below);
      if (kept && myrank < RPOST) selpos[myrank] = c*64 + t;
      if (t == 0){
        kb_sh[c & 1] = kb;
        keepw[c] = kb;
        int nc = cnt0 + __popcll(kb);
        if (nc >= RPOST){ nc = RPOST; done_sh = 1; }
        cnt_sh = nc;
      }
      kbp2 = kbp1; kbp1 = kb;
      dg_cur = dg_n; s1_cur = s1_n; s2_cur = s2_n; remv_c = remv_n;
    } else {
      // consume: apply kb(c-1) to remv[c+2+pw] from regs prefetched at chunk c-1
      int wpc = c + 2 + pw;
      if (c >= 1 && wpc < NW){
        ull kbp = kb_sh[(c-1) & 1];
        if (kbp){
          ull acc = 0;
          #pragma unroll
          for (int b=0;b<16;++b){
            acc |= (0ull - ((kbp >> (hh*32 + 2*b))   & 1ull)) & pre[b].x;
            acc |= (0ull - ((kbp >> (hh*32 + 2*b+1)) & 1ull)) & pre[b].y;
          }
          if (acc) atomicOr(&remv[wpc], acc);
        }
      }
      // prefetch rows for chunk c+1's consume: kb(c) -> remv[c+3+pw]
      int wpn = c + 3 + pw;
      if (c+1 < NW && wpn < NW){
        const ulonglong2* src =
          (const ulonglong2*)(maskT + (size_t)wpn*NA + (size_t)c*64) + hh*16;
        #pragma unroll
        for (int b=0;b<16;++b) pre[b] = src[b];
      }
    }
    __syncthreads();
    if (done_sh) break;
  }
  __syncthreads();
  // parallel fill path (<512 kept after full scan): suppressed positions, ascending
  int cnt0 = cnt_sh;
  if (cnt0 < RPOST){
    if (t < NW){
      int s = 0;
      for (int w2=0; w2<t; ++w2) s += __popcll(~keepw[w2]);
      base_sh[t] = s;
    }
    __syncthreads();
    for (int p = t; p < NA; p += 320){
      int w2 = p >> 6, b = p & 63;
      ull kw = keepw[w2];
      if (!((kw >> b) & 1ull)){
        int rank = cnt0 + base_sh[w2] + __popcll(~kw & ((1ull << b) - 1ull));
        if (rank < RPOST) selpos[rank] = p;
      }
    }
  }
  __syncthreads();
  for (int s=t; s<RPOST; s+=320){
    int pos = selpos[s];
    int orig = ord[pos];
    float4 b = ((const float4*)sboxes)[pos];
    out[s*10+0] = probs[orig*2+0];
    out[s*10+1] = probs[orig*2+1];
    out[s*10+2] = b.x; out[s*10+3] = b.y; out[s*10+4] = b.z; out[s*10+5] = b.w;
    ((float4*)selb)[s] = b;
  }
}

// ---------------- K5: ROIAlign (block = box, thread = channel) -> bf16 pooled ----------------
__global__ __launch_bounds__(256) void roialign(const float* __restrict__ feat,
    const float* __restrict__ selb, __hip_bfloat16* __restrict__ pooled){
  int r = blockIdx.x, c = threadIdx.x;
  float4 b = ((const float4*)selb)[r];
  int x0[6], x1[6], y0[6], y1[6];
  float wx[6], wy[6];
  #pragma unroll
  for (int s=0;s<6;++s){
    float off = ((float)s + 0.5f) / 6.0f;
    float fx = (b.x + off*b.z) / 32.0f - 0.5f;
    fx = fminf(fmaxf(fx, 0.0f), 47.0f);
    int xx0 = (int)floorf(fx);
    x0[s] = xx0; x1[s] = min(xx0+1, 47); wx[s] = fx - (float)xx0;
    float fy = (b.y + off*b.w) / 32.0f - 0.5f;
    fy = fminf(fmaxf(fy, 0.0f), 47.0f);
    int yy0 = (int)floorf(fy);
    y0[s] = yy0; y1[s] = min(yy0+1, 47); wy[s] = fy - (float)yy0;
  }
  #pragma unroll
  for (int ty=0;ty<3;++ty){
    #pragma unroll
    for (int tx=0;tx<3;++tx){
      float sum = 0.0f;
      #pragma unroll
      for (int py=0;py<2;++py){
        #pragma unroll
        for (int px=0;px<2;++px){
          int sy = ty*2+py, sx = tx*2+px;
          float wxx = wx[sx], wyy = wy[sy];
          float v00 = feat[(y0[sy]*MGRID + x0[sx])*CCH + c];
          float v01 = feat[(y0[sy]*MGRID + x1[sx])*CCH + c];
          float v10 = feat[(y1[sy]*MGRID + x0[sx])*CCH + c];
          float v11 = feat[(y1[sy]*MGRID + x1[sx])*CCH + c];
          sum += v00*(1.0f-wyy)*(1.0f-wxx) + v01*(1.0f-wyy)*wxx
               + v10*wyy*(1.0f-wxx)        + v11*wyy*wxx;
        }
      }
      pooled[((r*9) + ty*3 + tx)*CCH + c] = __float2bfloat16(sum * 0.25f);
    }
  }
}

// ---------------- K6: FC1 bf16 MFMA, 2-way K-split ----------------
__global__ __launch_bounds__(256) void fc1_mfma(const ushort* __restrict__ A,
    const ushort* __restrict__ Bt, const float* __restrict__ bias,
    float* __restrict__ Hp){
  __shared__ ushort As[4096];   // 64 rows x 64 k bf16, XOR-swizzled 16B chunks
  __shared__ ushort Bs[4096];
  const int t = threadIdx.x;
  const int bn = blockIdx.x, bm = blockIdx.y, bz = blockIdx.z;
  const int wv = t >> 6, lane = t & 63;
  const int wm = (wv >> 1) * 32, wn = (wv & 1) * 32;

  const int r0 = t >> 3, kc = t & 7;
  const int r1 = r0 + 32;
  const int kbase = bz * 144;   // 1152 k * 2B / 16B
  const float4* gA0 = (const float4*)A  + (size_t)(bm*64 + r0)*288 + kbase + kc;
  const float4* gA1 = (const float4*)A  + (size_t)(bm*64 + r1)*288 + kbase + kc;
  const float4* gB0 = (const float4*)Bt + (size_t)(bn*64 + r0)*288 + kbase + kc;
  const float4* gB1 = (const float4*)Bt + (size_t)(bn*64 + r1)*288 + kbase + kc;
  float4* sA0 = (float4*)As + ((r0<<3) | (kc ^ (r0&7)));
  float4* sA1 = (float4*)As + ((r1<<3) | (kc ^ (r1&7)));
  float4* sB0 = (float4*)Bs + ((r0<<3) | (kc ^ (r0&7)));
  float4* sB1 = (float4*)Bs + ((r1<<3) | (kc ^ (r1&7)));

  const int fr = lane & 15, fkg = lane >> 4;
  const int arow0 = wm + fr,      arow1 = wm + 16 + fr;
  const int brow0 = wn + fr,      brow1 = wn + 16 + fr;

  f32x4 acc00{}, acc01{}, acc10{}, acc11{};

  const int KT = 18;            // 1152 / 64
  float4 pa0 = gA0[0], pa1 = gA1[0], pb0 = gB0[0], pb1 = gB1[0];
  for (int kt = 0; kt < KT; ++kt){
    __syncthreads();
    *sA0 = pa0; *sA1 = pa1; *sB0 = pb0; *sB1 = pb1;
    if (kt + 1 < KT){
      pa0 = gA0[(kt+1)*8]; pa1 = gA1[(kt+1)*8];
      pb0 = gB0[(kt+1)*8]; pb1 = gB1[(kt+1)*8];
    }
    __syncthreads();
    #pragma unroll
    for (int kk2 = 0; kk2 < 2; ++kk2){
      int kidx = fkg + kk2*4;
      short8v a0 = *(const short8v*)(As + ((((arow0<<3) | (kidx ^ (arow0&7)))) << 3));
      short8v a1 = *(const short8v*)(As + ((((arow1<<3) | (kidx ^ (arow1&7)))) << 3));
      short8v b0 = *(const short8v*)(Bs + ((((brow0<<3) | (kidx ^ (brow0&7)))) << 3));
      short8v b1 = *(const short8v*)(Bs + ((((brow1<<3) | (kidx ^ (brow1&7)))) << 3));
      acc00 = __builtin_amdgcn_mfma_f32_16x16x32_bf16(a0, b0, acc00, 0, 0, 0);
      acc01 = __builtin_amdgcn_mfma_f32_16x16x32_bf16(a0, b1, acc01, 0, 0, 0);
      acc10 = __builtin_amdgcn_mfma_f32_16x16x32_bf16(a1, b0, acc10, 0, 0, 0);
      acc11 = __builtin_amdgcn_mfma_f32_16x16x32_bf16(a1, b1, acc11, 0, 0, 0);
    }
  }
  float* H = Hp + (size_t)bz * 512 * NHID;
  const int orow = bm*64 + wm + (lane>>4)*4;
  const int ocol = bn*64 + wn + (lane&15);
  #pragma unroll
  for (int i=0;i<2;++i){
    #pragma unroll
    for (int j=0;j<2;++j){
      f32x4 a = (i==0) ? ((j==0)?acc00:acc01) : ((j==0)?acc10:acc11);
      #pragma unroll
      for (int reg=0;reg<4;++reg){
        int row = orow + i*16 + reg;
        int col = ocol + j*16;
        float v = a[reg] + (bz == 0 ? bias[col] : 0.0f);
        H[(size_t)row*NHID + col] = v;        // relu deferred to fc2
      }
    }
  }
}

// ---------------- K7: FC2 (sums K-split partials + relu) + unparameterize ----------------
__global__ __launch_bounds__(64) void fc2(const float* __restrict__ h0,
    const float* __restrict__ h1, const float* __restrict__ W2,
    const float* __restrict__ b2, const float* __restrict__ selb,
    float* __restrict__ out){
  int r = blockIdx.x, lane = threadIdx.x;
  float a0=0,a1=0,a2=0,a3=0;
  #pragma unroll 4
  for (int it=0; it<16; ++it){
    int k = it*64 + lane;
    float hv = fmaxf(h0[(size_t)r*NHID + k] + h1[(size_t)r*NHID + k], 0.0f);
    float4 w = ((const float4*)W2)[k];
    a0 += hv*w.x; a1 += hv*w.y; a2 += hv*w.z; a3 += hv*w.w;
  }
  #pragma unroll
  for (int off=32; off>0; off>>=1){
    a0 += __shfl_down(a0, off);
    a1 += __shfl_down(a1, off);
    a2 += __shfl_down(a2, off);
    a3 += __shfl_down(a3, off);
  }
  if (lane == 0){
    float4 b = ((const float4*)selb)[r];
    float r0 = a0 + b2[0], r1 = a1 + b2[1], r2 = a2 + b2[2], r3 = a3 + b2[3];
    float cxa = b.x + b.z*0.5f, cya = b.y + b.w*0.5f;
    float cx = r0*b.z + cxa, cy = r1*b.w + cya;
    float w  = b.z*expf(r2),  hh = b.w*expf(r3);
    out[r*10+6] = cx - w*0.5f;
    out[r*10+7] = cy - hh*0.5f;
    out[r*10+8] = w;
    out[r*10+9] = hh;
  }
}

extern "C" void kernel_launch(void* const* d_in, const int* in_sizes, int n_in,
                              void* d_out, int out_size, void* d_ws, size_t ws_size,
                              hipStream_t stream) {
  const float* feat    = (const float*)d_in[0];
  const float* anchors = (const float*)d_in[1];
  const float* Wobj    = (const float*)d_in[2];
  const float* bobj    = (const float*)d_in[3];
  const float* Wreg    = (const float*)d_in[4];
  const float* breg    = (const float*)d_in[5];
  const float* Wfc1    = (const float*)d_in[6];
  const float* bfc1    = (const float*)d_in[7];
  const float* Wfc2    = (const float*)d_in[8];
  const float* bfc2    = (const float*)d_in[9];
  float* out = (float*)d_out;
  char* ws = (char*)d_ws;

  float* probs  = (float*)(ws + 165888);     // 55296
  float* boxes  = (float*)(ws + 221184);     // 110592
  ull*   keys   = (ull*)  (ws + 331776);     // 55296
  int*   ord    = (int*)  (ws + 387072);     // 27648
  float* sboxes = (float*)(ws + 414720);     // 110592
  unsigned* rank_acc = (unsigned*)(ws + 525312); // 27648
  ull*   maskT  = (ull*)  (ws + 1271808);    // 5971968
  float* selb   = (float*)(ws + 7243776);    // 8192
  __hip_bfloat16* pooled = (__hip_bfloat16*)(ws + 7251968); // 2359296
  float* h      = (float*)(ws + 9611264);    // 2x 2097152 (K-split partials)
  ushort* Wt    = (ushort*)(ws + 13805568);  // 4718592 (end 18524160)

  float* h0 = h;
  float* h1 = h + 512*NHID;

  hipLaunchKernelGGL(rpn_anchor_wcvt, dim3(2496),  dim3(256), 0, stream,
                     feat, Wobj, bobj, Wreg, breg, anchors, probs, boxes, keys, Wfc1, Wt, rank_acc);
  hipLaunchKernelGGL(rank_fused,   dim3(27,27),  dim3(256), 0, stream, keys, boxes, rank_acc, ord, sboxes);
  hipLaunchKernelGGL(iou_mask,     dim3(1525),   dim3(256), 0, stream, sboxes, maskT);
  hipLaunchKernelGGL(nms,          dim3(1),      dim3(320), 0, stream, maskT, ord, sboxes, probs, out, selb);
  hipLaunchKernelGGL(roialign,     dim3(512),    dim3(256), 0, stream, feat, selb, pooled);
  hipLaunchKernelGGL(fc1_mfma,     dim3(16,8,2), dim3(256), 0, stream, (const ushort*)pooled, Wt, bfc1, h);
  hipLaunchKernelGGL(fc2,          dim3(512),    dim3(64),  0, stream, h0, h1, Wfc2, bfc2, selb, out);
}